// Round 12
// baseline (338.659 us; speedup 1.0000x reference)
//
#include <hip/hip_runtime.h>
#include <hip/hip_bf16.h>

#define HH 100      // hidden size
#define HP 112      // padded hidden (7*16)
#define MT 7        // 16-wide tiles over hidden
#define KS 116      // row stride (bf16): S=58 words -> 16 distinct banks (R9: 6e7->1.9e6)
#define RB 128      // rows per block (4 waves * 32 rows)
#define LL 3
#define INV2PI 0.15915494309189535f
#define TWO_PI 6.2831853071795865f

typedef __attribute__((ext_vector_type(4))) short bf16x4;
typedef __attribute__((ext_vector_type(4))) float f32x4;
typedef __attribute__((ext_vector_type(2))) float f32x2;

// D = A(16x16) @ B(16x16) + C via v_mfma_f32_16x16x16_bf16 (gfx950).
// A: lane m=l&15 holds k=(l>>4)*4+i ; B: same; C/D: col=l&15, row=(l>>4)*4+reg.
// Intrinsic (not asm) so the compiler inserts MFMA<->VALU hazard waits (R3 NaN).
__device__ __forceinline__ f32x4 mfma16(bf16x4 a, bf16x4 b, f32x4 c) {
#if __has_builtin(__builtin_amdgcn_mfma_f32_16x16x16bf16_1k)
    return __builtin_amdgcn_mfma_f32_16x16x16bf16_1k(a, b, c, 0, 0, 0);
#else
    asm volatile("s_nop 1\n\t"
                 "v_mfma_f32_16x16x16_bf16 %0, %1, %2, %0\n\t"
                 "s_nop 7\n\t"
                 "s_nop 7"
                 : "+v"(c) : "v"(a), "v"(b));
    return c;
#endif
}

// LOAD-BEARING (R7): fences stop the pre-RA scheduler hoisting all 49 ds_read
// A-frags per MFMA pass -> arch-VGPR spill (R4-R6: 5-7 GB scratch traffic).
__device__ __forceinline__ void sfence() { __builtin_amdgcn_sched_barrier(0); }

// Truncating f32->bf16 pack via v_perm (1 instr/pair vs ~7 for RNE). R10 win.
__device__ __forceinline__ bf16x4 pack4(float a0, float a1, float a2, float a3) {
    union { unsigned u[2]; bf16x4 v; } r;
    r.u[0] = __builtin_amdgcn_perm(__float_as_uint(a1), __float_as_uint(a0), 0x07060302);
    r.u[1] = __builtin_amdgcn_perm(__float_as_uint(a3), __float_as_uint(a2), 0x07060302);
    return r.v;
}

__device__ __forceinline__ short f2b(float f) {   // staging only (not hot path)
    union { __hip_bfloat16 h; short s; } u;
    u.h = __float2bfloat16(f);
    return u.s;
}
__device__ __forceinline__ float b2f(short s) {
    union { unsigned u; float f; } v;
    v.u = ((unsigned)(unsigned short)s) << 16;
    return v.f;
}
__device__ __forceinline__ f32x2 unpack2(unsigned u) {
    f32x2 r;
    r[0] = __uint_as_float(u << 16);
    r[1] = __uint_as_float(u & 0xffff0000u);
    return r;
}
__device__ __forceinline__ f32x2 vfma2(f32x2 a, f32x2 b, f32x2 c) {
    return __builtin_elementwise_fma(a, b, c);   // -> v_pk_fma_f32
}

// LDS = 51968 + 448+448+224+224+224 = 53536 <= 53760 (R9-proven 3-blocks/CU).
// W1 tables pre-scaled by 1/(2pi) -> raw v_sin/v_cos (no prescale mul); the
// scaled wx/wy in the epilogue contraction is undone by one x2pi at the end.
// b2 lives in W2 column 100 (B-frag forced to 1.0 there) -> no b2 add in g2.
__global__ __launch_bounds__(256, 3) void sympnet_kernel(
    const float* __restrict__ z,   const float* __restrict__ t,
    const float* __restrict__ Wq1, const float* __restrict__ bq1,
    const float* __restrict__ Wq2, const float* __restrict__ bq2,
    const float* __restrict__ wq3,
    const float* __restrict__ Wp1, const float* __restrict__ bp1,
    const float* __restrict__ Wp2, const float* __restrict__ bp2,
    const float* __restrict__ wp3,
    float* __restrict__ out)
{
    __shared__ __align__(16) short  sW2b[HP * KS];  // W2[j][k] bf16 (+b2 in k=100)
    __shared__ __align__(16) short  sW2T[HP * KS];  // W2^T[k'][j] bf16
    __shared__ __align__(16) float  sWx[HP];        // W1[k][0]/(2pi) f32
    __shared__ __align__(16) float  sWy[HP];        // W1[k][1]/(2pi) f32
    __shared__ __align__(16) short  sWz[HP];        // W1[k][2]/(2pi) bf16
    __shared__ __align__(16) short  sWb[HP];        // b1[k]/(2pi)    bf16
    __shared__ __align__(16) short  sw3[HP];        // w3[j] bf16

    const int tid = threadIdx.x;
    const int m   = tid & 15;          // lane & 15
    const int g   = (tid >> 4) & 3;    // lane-group within wave
    const int waveRow = (tid >> 6) * 32;
    const int gbase   = blockIdx.x * RB;

    // State in registers; all 4 lane-groups hold identical copies (the shfl
    // butterfly gives every lane the full delta -> consistent updates).
    const int r0 = gbase + waveRow + m;
    const int r1 = r0 + 16;
    float4 st0 = reinterpret_cast<const float4*>(z)[r0];
    float4 st1 = reinterpret_cast<const float4*>(z)[r1];
    const float tr0 = t[r0];
    const float tr1 = t[r1];

    #pragma unroll 1
    for (int layer = 0; layer < LL; ++layer) {
      #pragma unroll 1
      for (int pot = 0; pot < 2; ++pot) {
        const float* gW2 = (pot ? Wp2 : Wq2) + layer * (HH * HH);
        const float* gW1 = (pot ? Wp1 : Wq1) + layer * (HH * 3);
        const float* gb1 = (pot ? bp1 : bq1) + layer * HH;
        const float* gb2 = (pot ? bp2 : bq2) + layer * HH;
        const float* gw3 = (pot ? wp3 : wq3) + layer * HH;

        __syncthreads();   // prior stage done with weight buffers

        // ---- stage sW2b (coalesced) + small weights ----
        #pragma unroll 1
        for (int idx = tid; idx < HP * 28; idx += 256) {
            const int j  = idx / 28;
            const int kc = idx - j * 28;       // 28 bf16x4 chunks per row (25 real)
            bf16x4 v = {0, 0, 0, 0};
            if (j < HH) {
                if (kc < 25) {
                    const float4 w = reinterpret_cast<const float4*>(gW2)[j * 25 + kc];
                    v[0] = f2b(w.x); v[1] = f2b(w.y); v[2] = f2b(w.z); v[3] = f2b(w.w);
                } else if (kc == 25) {
                    v[0] = f2b(gb2[j]);        // b2 -> k=100 column
                }
            }
            *reinterpret_cast<bf16x4*>(&sW2b[j * KS + 4 * kc]) = v;
        }
        if (tid < HP) {
            const bool ok = tid < HH;
            sWx[tid] = ok ? gW1[tid * 3]     * INV2PI : 0.f;
            sWy[tid] = ok ? gW1[tid * 3 + 1] * INV2PI : 0.f;
            sWz[tid] = ok ? f2b(gW1[tid * 3 + 2] * INV2PI) : (short)0;
            sWb[tid] = ok ? f2b(gb1[tid] * INV2PI)         : (short)0;
            sw3[tid] = ok ? f2b(gw3[tid])                  : (short)0;
        }
        __syncthreads();

        // ---- transpose sW2b -> sW2T in LDS (b2 column lands in row 100 of
        // sW2T; harmless: epilogue wx/wy[k=100]=0 kills its contribution) ----
        #pragma unroll 1
        for (int idx = tid; idx < HP * 28; idx += 256) {
            const int kp = idx % HP;
            const int jc = idx / HP;        // 0..27
            bf16x4 v;
            #pragma unroll
            for (int i = 0; i < 4; ++i)
                v[i] = sW2b[(4 * jc + i) * KS + kp];
            *reinterpret_cast<bf16x4*>(&sW2T[kp * KS + 4 * jc]) = v;
        }
        __syncthreads();

        const float x00 = pot ? st0.z : st0.x, x01 = pot ? st0.w : st0.y;
        const float x10 = pot ? st1.z : st1.x, x11 = pot ? st1.w : st1.y;
        const f32x2 x00v = {x00, x00}, x01v = {x01, x01};
        const f32x2 x10v = {x10, x10}, x11v = {x11, x11};

        float dsav00 = 0.f, dsav01 = 0.f, dsav10 = 0.f, dsav11 = 0.f;
        float df00 = 0.f, df01 = 0.f, df10 = 0.f, df11 = 0.f;

        #pragma unroll 1
        for (int e = 0; e < 2; ++e) {
          const float xt0 = e ? 0.f : tr0;
          const float xt1 = e ? 0.f : tr1;
          const f32x2 xt0v = {xt0, xt0}, xt1v = {xt1, xt1};

          // ---- stage 1: h'=h/(2pi); sin -> B-frags, cos -> register cache.
          bf16x4 sf[MT][2];
          f32x4  cosr[MT][2];              // cos(h1) cache (R12): kills epilogue recompute
          #pragma unroll
          for (int mt = 0; mt < MT; ++mt) {
            float sA[4], sB[4];
            #pragma unroll
            for (int rp = 0; rp < 2; ++rp) {
              const int kb = 16 * mt + 4 * g + 2 * rp;
              const f32x2 wx = *reinterpret_cast<const f32x2*>(&sWx[kb]);
              const f32x2 wy = *reinterpret_cast<const f32x2*>(&sWy[kb]);
              const f32x2 wz = unpack2(*reinterpret_cast<const unsigned*>(&sWz[kb]));
              const f32x2 wb = unpack2(*reinterpret_cast<const unsigned*>(&sWb[kb]));
              const f32x2 h0 = vfma2(wx, x00v, vfma2(wy, x01v, vfma2(wz, xt0v, wb)));
              const f32x2 h1 = vfma2(wx, x10v, vfma2(wy, x11v, vfma2(wz, xt1v, wb)));
              sA[2 * rp]     = __builtin_amdgcn_sinf(h0[0]);
              sA[2 * rp + 1] = __builtin_amdgcn_sinf(h0[1]);
              sB[2 * rp]     = __builtin_amdgcn_sinf(h1[0]);
              sB[2 * rp + 1] = __builtin_amdgcn_sinf(h1[1]);
              cosr[mt][0][2 * rp]     = __builtin_amdgcn_cosf(h0[0]);
              cosr[mt][0][2 * rp + 1] = __builtin_amdgcn_cosf(h0[1]);
              cosr[mt][1][2 * rp]     = __builtin_amdgcn_cosf(h1[0]);
              cosr[mt][1][2 * rp + 1] = __builtin_amdgcn_cosf(h1[1]);
            }
            if (mt == 6 && g == 1) { sA[0] = 1.f; sB[0] = 1.f; }  // k=100: b2 lane
            sf[mt][0] = pack4(sA[0], sA[1], sA[2], sA[3]);
            sf[mt][1] = pack4(sB[0], sB[1], sB[2], sB[3]);
            if (mt & 1) sfence();
          }
          sfence();

          // pass 1 (transposed): (H2+b2)^T[j][row] = W2aug @ [S1;1]^T
          f32x4 acc[MT][2];
          #pragma unroll
          for (int mt = 0; mt < MT; ++mt) { acc[mt][0] = (f32x4)0.f; acc[mt][1] = (f32x4)0.f; }
          #pragma unroll
          for (int kt = 0; kt < MT; ++kt) {
            #pragma unroll
            for (int mt = 0; mt < MT; ++mt) {
              const bf16x4 a = *reinterpret_cast<const bf16x4*>(
                  &sW2b[(16 * mt + m) * KS + 16 * kt + 4 * g]);
              acc[mt][0] = mfma16(a, sf[kt][0], acc[mt][0]);
              acc[mt][1] = mfma16(a, sf[kt][1], acc[mt][1]);
            }
            if (kt & 1) sfence();
          }
          sfence();

          // g2 = cos(h2+b2)*w3 (b2 already in acc); reuse sf for pass-2 B
          #pragma unroll
          for (int mt = 0; mt < MT; ++mt) {
            const bf16x4 w3v = *reinterpret_cast<const bf16x4*>(&sw3[16 * mt + 4 * g]);
            float gA[4], gB[4];
            #pragma unroll
            for (int r = 0; r < 4; ++r) {
              const float w3 = b2f(w3v[r]);
              gA[r] = __cosf(acc[mt][0][r]) * w3;
              gB[r] = __cosf(acc[mt][1][r]) * w3;
            }
            sf[mt][0] = pack4(gA[0], gA[1], gA[2], gA[3]);
            sf[mt][1] = pack4(gB[0], gB[1], gB[2], gB[3]);
            if (mt & 1) sfence();
          }
          sfence();

          // pass 2 (transposed): G1^T[k'][row] = W2^T @ G2^T (reuse acc)
          #pragma unroll
          for (int mt = 0; mt < MT; ++mt) { acc[mt][0] = (f32x4)0.f; acc[mt][1] = (f32x4)0.f; }
          #pragma unroll
          for (int kt = 0; kt < MT; ++kt) {
            #pragma unroll
            for (int mt = 0; mt < MT; ++mt) {
              const bf16x4 a = *reinterpret_cast<const bf16x4*>(
                  &sW2T[(16 * mt + m) * KS + 16 * kt + 4 * g]);
              acc[mt][0] = mfma16(a, sf[kt][0], acc[mt][0]);
              acc[mt][1] = mfma16(a, sf[kt][1], acc[mt][1]);
            }
            if (kt & 1) sfence();
          }
          sfence();

          // epilogue: delta = 2pi * sum_k G1*cosr*W1scaled[:,0:2]
          f32x2 pc00 = {0.f, 0.f}, pc01 = {0.f, 0.f};
          f32x2 pc10 = {0.f, 0.f}, pc11 = {0.f, 0.f};
          #pragma unroll
          for (int mt = 0; mt < MT; ++mt) {
            #pragma unroll
            for (int rp = 0; rp < 2; ++rp) {
              const int kb = 16 * mt + 4 * g + 2 * rp;
              const f32x2 wx = *reinterpret_cast<const f32x2*>(&sWx[kb]);
              const f32x2 wy = *reinterpret_cast<const f32x2*>(&sWy[kb]);
              f32x2 c0, c1, a0p, a1p;
              c0[0] = cosr[mt][0][2 * rp]; c0[1] = cosr[mt][0][2 * rp + 1];
              c1[0] = cosr[mt][1][2 * rp]; c1[1] = cosr[mt][1][2 * rp + 1];
              a0p[0] = acc[mt][0][2 * rp]; a0p[1] = acc[mt][0][2 * rp + 1];
              a1p[0] = acc[mt][1][2 * rp]; a1p[1] = acc[mt][1][2 * rp + 1];
              const f32x2 e0 = a0p * c0;
              const f32x2 e1 = a1p * c1;
              pc00 = vfma2(e0, wx, pc00); pc01 = vfma2(e0, wy, pc01);
              pc10 = vfma2(e1, wx, pc10); pc11 = vfma2(e1, wy, pc11);
            }
            if (mt & 1) sfence();
          }
          sfence();

          float p00 = (pc00[0] + pc00[1]) * TWO_PI;
          float p01 = (pc01[0] + pc01[1]) * TWO_PI;
          float p10 = (pc10[0] + pc10[1]) * TWO_PI;
          float p11 = (pc11[0] + pc11[1]) * TWO_PI;

          // butterfly -> ALL lanes end with the full sum (enables register state)
          p00 += __shfl_xor(p00, 16); p00 += __shfl_xor(p00, 32);
          p01 += __shfl_xor(p01, 16); p01 += __shfl_xor(p01, 32);
          p10 += __shfl_xor(p10, 16); p10 += __shfl_xor(p10, 32);
          p11 += __shfl_xor(p11, 16); p11 += __shfl_xor(p11, 32);

          if (e == 0) { dsav00 = p00; dsav01 = p01; dsav10 = p10; dsav11 = p11; }
          else {
            df00 = dsav00 - p00; df01 = dsav01 - p01;
            df10 = dsav10 - p10; df11 = dsav11 - p11;
          }
        } // e

        // redundant (identical) state update in every lane
        if (pot == 0) { st0.z -= df00; st0.w -= df01; st1.z -= df10; st1.w -= df11; }
        else          { st0.x += df00; st0.y += df01; st1.x += df10; st1.y += df11; }
      } // pot
    } // layer

    if (g == 0) {
        reinterpret_cast<float4*>(out)[r0] = st0;
        reinterpret_cast<float4*>(out)[r1] = st1;
    }
}

extern "C" void kernel_launch(void* const* d_in, const int* in_sizes, int n_in,
                              void* d_out, int out_size, void* d_ws, size_t ws_size,
                              hipStream_t stream) {
    const float* z   = (const float*)d_in[0];
    const float* t   = (const float*)d_in[1];
    const float* Wq1 = (const float*)d_in[2];
    const float* bq1 = (const float*)d_in[3];
    const float* Wq2 = (const float*)d_in[4];
    const float* bq2 = (const float*)d_in[5];
    const float* wq3 = (const float*)d_in[6];
    const float* Wp1 = (const float*)d_in[7];
    const float* bp1 = (const float*)d_in[8];
    const float* Wp2 = (const float*)d_in[9];
    const float* bp2 = (const float*)d_in[10];
    const float* wp3 = (const float*)d_in[11];
    float* out = (float*)d_out;

    const int B = in_sizes[1];          // 131072 rows
    const int blocks = B / RB;          // 1024 blocks

    sympnet_kernel<<<blocks, 256, 0, stream>>>(
        z, t, Wq1, bq1, Wq2, bq2, wq3, Wp1, bp1, Wp2, bp2, wp3, out);
}

// Round 13
// 260.933 us; speedup vs baseline: 1.2979x; 1.2979x over previous
//
#include <hip/hip_runtime.h>
#include <hip/hip_bf16.h>

#define HH 100      // hidden size
#define HP 112      // padded hidden (7*16)
#define MT 7        // 16-wide tiles over hidden
#define KS 116      // row stride (bf16): S=58 words -> 16 distinct banks (R9: 6e7->1.9e6)
#define RB 128      // rows per block (4 waves * 32 rows)
#define LL 3
#define INV2PI 0.15915494309189535f
#define TWO_PI 6.2831853071795865f

typedef __attribute__((ext_vector_type(4))) short bf16x4;
typedef __attribute__((ext_vector_type(4))) float f32x4;
typedef __attribute__((ext_vector_type(2))) float f32x2;

// D = A(16x16) @ B(16x16) + C via v_mfma_f32_16x16x16_bf16 (gfx950).
// A: lane m=l&15 holds k=(l>>4)*4+i ; B: same; C/D: col=l&15, row=(l>>4)*4+reg.
// Intrinsic (not asm) so the compiler inserts MFMA<->VALU hazard waits (R3 NaN).
__device__ __forceinline__ f32x4 mfma16(bf16x4 a, bf16x4 b, f32x4 c) {
#if __has_builtin(__builtin_amdgcn_mfma_f32_16x16x16bf16_1k)
    return __builtin_amdgcn_mfma_f32_16x16x16bf16_1k(a, b, c, 0, 0, 0);
#else
    asm volatile("s_nop 1\n\t"
                 "v_mfma_f32_16x16x16_bf16 %0, %1, %2, %0\n\t"
                 "s_nop 7\n\t"
                 "s_nop 7"
                 : "+v"(c) : "v"(a), "v"(b));
    return c;
#endif
}

// LOAD-BEARING (R7): fences stop the pre-RA scheduler hoisting all 49 ds_read
// A-frags per MFMA pass -> arch-VGPR spill (R4-R6: 5-7 GB scratch traffic).
__device__ __forceinline__ void sfence() { __builtin_amdgcn_sched_barrier(0); }

// Truncating f32->bf16 pack via v_perm (1 instr/pair vs ~7 for RNE). R10 win.
__device__ __forceinline__ bf16x4 pack4(float a0, float a1, float a2, float a3) {
    union { unsigned u[2]; bf16x4 v; } r;
    r.u[0] = __builtin_amdgcn_perm(__float_as_uint(a1), __float_as_uint(a0), 0x07060302);
    r.u[1] = __builtin_amdgcn_perm(__float_as_uint(a3), __float_as_uint(a2), 0x07060302);
    return r.v;
}

__device__ __forceinline__ short f2b(float f) {   // staging only (not hot path)
    union { __hip_bfloat16 h; short s; } u;
    u.h = __float2bfloat16(f);
    return u.s;
}
__device__ __forceinline__ float b2f(short s) {
    union { unsigned u; float f; } v;
    v.u = ((unsigned)(unsigned short)s) << 16;
    return v.f;
}
__device__ __forceinline__ f32x2 unpack2(unsigned u) {
    f32x2 r;
    r[0] = __uint_as_float(u << 16);
    r[1] = __uint_as_float(u & 0xffff0000u);
    return r;
}
__device__ __forceinline__ f32x2 vfma2(f32x2 a, f32x2 b, f32x2 c) {
    return __builtin_elementwise_fma(a, b, c);   // -> v_pk_fma_f32
}

// LDS = 51968 + 448+448+224+224+224 = 53536 <= 53760 (R9-proven 3-blocks/CU).
// W1 tables pre-scaled by 1/(2pi) -> raw v_sin/v_cos; undone by one x2pi at
// the end of the contraction. b2 lives in W2 column k=100 (B-frag forced to
// 1.0 there) -> no b2 add in g2.
// NO cosr register cache: R12 proved 56 extra live f32s at 3 blocks/CU spill
// (232 MB scratch writes, VGPR stuck at 84 under the 168 unified budget).
// Epilogue recomputes h' instead — VALU is cheaper than scratch.
__global__ __launch_bounds__(256, 3) void sympnet_kernel(
    const float* __restrict__ z,   const float* __restrict__ t,
    const float* __restrict__ Wq1, const float* __restrict__ bq1,
    const float* __restrict__ Wq2, const float* __restrict__ bq2,
    const float* __restrict__ wq3,
    const float* __restrict__ Wp1, const float* __restrict__ bp1,
    const float* __restrict__ Wp2, const float* __restrict__ bp2,
    const float* __restrict__ wp3,
    float* __restrict__ out)
{
    __shared__ __align__(16) short  sW2b[HP * KS];  // W2[j][k] bf16 (+b2 in k=100)
    __shared__ __align__(16) short  sW2T[HP * KS];  // W2^T[k'][j] bf16
    __shared__ __align__(16) float  sWx[HP];        // W1[k][0]/(2pi) f32
    __shared__ __align__(16) float  sWy[HP];        // W1[k][1]/(2pi) f32
    __shared__ __align__(16) short  sWz[HP];        // W1[k][2]/(2pi) bf16
    __shared__ __align__(16) short  sWb[HP];        // b1[k]/(2pi)    bf16
    __shared__ __align__(16) short  sw3[HP];        // w3[j] bf16

    const int tid = threadIdx.x;
    const int m   = tid & 15;          // lane & 15
    const int g   = (tid >> 4) & 3;    // lane-group within wave
    const int waveRow = (tid >> 6) * 32;
    const int gbase   = blockIdx.x * RB;

    // State in registers; all 4 lane-groups hold identical copies (the shfl
    // butterfly gives every lane the full delta -> consistent updates).
    const int r0 = gbase + waveRow + m;
    const int r1 = r0 + 16;
    float4 st0 = reinterpret_cast<const float4*>(z)[r0];
    float4 st1 = reinterpret_cast<const float4*>(z)[r1];
    const float tr0 = t[r0];
    const float tr1 = t[r1];

    #pragma unroll 1
    for (int layer = 0; layer < LL; ++layer) {
      #pragma unroll 1
      for (int pot = 0; pot < 2; ++pot) {
        const float* gW2 = (pot ? Wp2 : Wq2) + layer * (HH * HH);
        const float* gW1 = (pot ? Wp1 : Wq1) + layer * (HH * 3);
        const float* gb1 = (pot ? bp1 : bq1) + layer * HH;
        const float* gb2 = (pot ? bp2 : bq2) + layer * HH;
        const float* gw3 = (pot ? wp3 : wq3) + layer * HH;

        __syncthreads();   // prior stage done with weight buffers

        // ---- stage sW2b (coalesced) + small weights ----
        #pragma unroll 1
        for (int idx = tid; idx < HP * 28; idx += 256) {
            const int j  = idx / 28;
            const int kc = idx - j * 28;       // 28 bf16x4 chunks per row (25 real)
            bf16x4 v = {0, 0, 0, 0};
            if (j < HH) {
                if (kc < 25) {
                    const float4 w = reinterpret_cast<const float4*>(gW2)[j * 25 + kc];
                    v[0] = f2b(w.x); v[1] = f2b(w.y); v[2] = f2b(w.z); v[3] = f2b(w.w);
                } else if (kc == 25) {
                    v[0] = f2b(gb2[j]);        // b2 -> k=100 column
                }
            }
            *reinterpret_cast<bf16x4*>(&sW2b[j * KS + 4 * kc]) = v;
        }
        if (tid < HP) {
            const bool ok = tid < HH;
            sWx[tid] = ok ? gW1[tid * 3]     * INV2PI : 0.f;
            sWy[tid] = ok ? gW1[tid * 3 + 1] * INV2PI : 0.f;
            sWz[tid] = ok ? f2b(gW1[tid * 3 + 2] * INV2PI) : (short)0;
            sWb[tid] = ok ? f2b(gb1[tid] * INV2PI)         : (short)0;
            sw3[tid] = ok ? f2b(gw3[tid])                  : (short)0;
        }
        __syncthreads();

        // ---- transpose sW2b -> sW2T in LDS (b2 column lands in row 100 of
        // sW2T; harmless: epilogue wx/wy[k=100]=0 kills its contribution) ----
        #pragma unroll 1
        for (int idx = tid; idx < HP * 28; idx += 256) {
            const int kp = idx % HP;
            const int jc = idx / HP;        // 0..27
            bf16x4 v;
            #pragma unroll
            for (int i = 0; i < 4; ++i)
                v[i] = sW2b[(4 * jc + i) * KS + kp];
            *reinterpret_cast<bf16x4*>(&sW2T[kp * KS + 4 * jc]) = v;
        }
        __syncthreads();

        const float x00 = pot ? st0.z : st0.x, x01 = pot ? st0.w : st0.y;
        const float x10 = pot ? st1.z : st1.x, x11 = pot ? st1.w : st1.y;
        const f32x2 x00v = {x00, x00}, x01v = {x01, x01};
        const f32x2 x10v = {x10, x10}, x11v = {x11, x11};

        float dsav00 = 0.f, dsav01 = 0.f, dsav10 = 0.f, dsav11 = 0.f;
        float df00 = 0.f, df01 = 0.f, df10 = 0.f, df11 = 0.f;

        #pragma unroll 1
        for (int e = 0; e < 2; ++e) {
          const float xt0 = e ? 0.f : tr0;
          const float xt1 = e ? 0.f : tr1;
          const f32x2 xt0v = {xt0, xt0}, xt1v = {xt1, xt1};

          // ---- stage 1: h'=h/(2pi); sin(2pi h') = v_sin(h') -> B-frags ----
          bf16x4 sf[MT][2];
          #pragma unroll
          for (int mt = 0; mt < MT; ++mt) {
            float sA[4], sB[4];
            #pragma unroll
            for (int rp = 0; rp < 2; ++rp) {
              const int kb = 16 * mt + 4 * g + 2 * rp;
              const f32x2 wx = *reinterpret_cast<const f32x2*>(&sWx[kb]);
              const f32x2 wy = *reinterpret_cast<const f32x2*>(&sWy[kb]);
              const f32x2 wz = unpack2(*reinterpret_cast<const unsigned*>(&sWz[kb]));
              const f32x2 wb = unpack2(*reinterpret_cast<const unsigned*>(&sWb[kb]));
              const f32x2 h0 = vfma2(wx, x00v, vfma2(wy, x01v, vfma2(wz, xt0v, wb)));
              const f32x2 h1 = vfma2(wx, x10v, vfma2(wy, x11v, vfma2(wz, xt1v, wb)));
              sA[2 * rp]     = __builtin_amdgcn_sinf(h0[0]);
              sA[2 * rp + 1] = __builtin_amdgcn_sinf(h0[1]);
              sB[2 * rp]     = __builtin_amdgcn_sinf(h1[0]);
              sB[2 * rp + 1] = __builtin_amdgcn_sinf(h1[1]);
            }
            if (mt == 6 && g == 1) { sA[0] = 1.f; sB[0] = 1.f; }  // k=100: b2 lane
            sf[mt][0] = pack4(sA[0], sA[1], sA[2], sA[3]);
            sf[mt][1] = pack4(sB[0], sB[1], sB[2], sB[3]);
            if (mt & 1) sfence();
          }
          sfence();

          // pass 1 (transposed): (H2+b2)^T[j][row] = W2aug @ [S1;1]^T
          f32x4 acc[MT][2];
          #pragma unroll
          for (int mt = 0; mt < MT; ++mt) { acc[mt][0] = (f32x4)0.f; acc[mt][1] = (f32x4)0.f; }
          #pragma unroll
          for (int kt = 0; kt < MT; ++kt) {
            #pragma unroll
            for (int mt = 0; mt < MT; ++mt) {
              const bf16x4 a = *reinterpret_cast<const bf16x4*>(
                  &sW2b[(16 * mt + m) * KS + 16 * kt + 4 * g]);
              acc[mt][0] = mfma16(a, sf[kt][0], acc[mt][0]);
              acc[mt][1] = mfma16(a, sf[kt][1], acc[mt][1]);
            }
            if (kt & 1) sfence();
          }
          sfence();

          // g2 = cos(h2+b2)*w3 (b2 already in acc); reuse sf for pass-2 B
          #pragma unroll
          for (int mt = 0; mt < MT; ++mt) {
            const bf16x4 w3v = *reinterpret_cast<const bf16x4*>(&sw3[16 * mt + 4 * g]);
            float gA[4], gB[4];
            #pragma unroll
            for (int r = 0; r < 4; ++r) {
              const float w3 = b2f(w3v[r]);
              gA[r] = __cosf(acc[mt][0][r]) * w3;
              gB[r] = __cosf(acc[mt][1][r]) * w3;
            }
            sf[mt][0] = pack4(gA[0], gA[1], gA[2], gA[3]);
            sf[mt][1] = pack4(gB[0], gB[1], gB[2], gB[3]);
            if (mt & 1) sfence();
          }
          sfence();

          // pass 2 (transposed): G1^T[k'][row] = W2^T @ G2^T (reuse acc)
          #pragma unroll
          for (int mt = 0; mt < MT; ++mt) { acc[mt][0] = (f32x4)0.f; acc[mt][1] = (f32x4)0.f; }
          #pragma unroll
          for (int kt = 0; kt < MT; ++kt) {
            #pragma unroll
            for (int mt = 0; mt < MT; ++mt) {
              const bf16x4 a = *reinterpret_cast<const bf16x4*>(
                  &sW2T[(16 * mt + m) * KS + 16 * kt + 4 * g]);
              acc[mt][0] = mfma16(a, sf[kt][0], acc[mt][0]);
              acc[mt][1] = mfma16(a, sf[kt][1], acc[mt][1]);
            }
            if (kt & 1) sfence();
          }
          sfence();

          // epilogue: recompute h' (pre-scaled tables), raw v_cos, contract.
          f32x2 pc00 = {0.f, 0.f}, pc01 = {0.f, 0.f};
          f32x2 pc10 = {0.f, 0.f}, pc11 = {0.f, 0.f};
          #pragma unroll
          for (int mt = 0; mt < MT; ++mt) {
            #pragma unroll
            for (int rp = 0; rp < 2; ++rp) {
              const int kb = 16 * mt + 4 * g + 2 * rp;
              const f32x2 wx = *reinterpret_cast<const f32x2*>(&sWx[kb]);
              const f32x2 wy = *reinterpret_cast<const f32x2*>(&sWy[kb]);
              const f32x2 wz = unpack2(*reinterpret_cast<const unsigned*>(&sWz[kb]));
              const f32x2 wb = unpack2(*reinterpret_cast<const unsigned*>(&sWb[kb]));
              const f32x2 h0 = vfma2(wx, x00v, vfma2(wy, x01v, vfma2(wz, xt0v, wb)));
              const f32x2 h1 = vfma2(wx, x10v, vfma2(wy, x11v, vfma2(wz, xt1v, wb)));
              f32x2 c0, c1, a0p, a1p;
              c0[0] = __builtin_amdgcn_cosf(h0[0]); c0[1] = __builtin_amdgcn_cosf(h0[1]);
              c1[0] = __builtin_amdgcn_cosf(h1[0]); c1[1] = __builtin_amdgcn_cosf(h1[1]);
              a0p[0] = acc[mt][0][2 * rp]; a0p[1] = acc[mt][0][2 * rp + 1];
              a1p[0] = acc[mt][1][2 * rp]; a1p[1] = acc[mt][1][2 * rp + 1];
              const f32x2 e0 = a0p * c0;
              const f32x2 e1 = a1p * c1;
              pc00 = vfma2(e0, wx, pc00); pc01 = vfma2(e0, wy, pc01);
              pc10 = vfma2(e1, wx, pc10); pc11 = vfma2(e1, wy, pc11);
            }
            if (mt & 1) sfence();
          }
          sfence();

          float p00 = (pc00[0] + pc00[1]) * TWO_PI;
          float p01 = (pc01[0] + pc01[1]) * TWO_PI;
          float p10 = (pc10[0] + pc10[1]) * TWO_PI;
          float p11 = (pc11[0] + pc11[1]) * TWO_PI;

          // butterfly -> ALL lanes end with the full sum (enables register state)
          p00 += __shfl_xor(p00, 16); p00 += __shfl_xor(p00, 32);
          p01 += __shfl_xor(p01, 16); p01 += __shfl_xor(p01, 32);
          p10 += __shfl_xor(p10, 16); p10 += __shfl_xor(p10, 32);
          p11 += __shfl_xor(p11, 16); p11 += __shfl_xor(p11, 32);

          if (e == 0) { dsav00 = p00; dsav01 = p01; dsav10 = p10; dsav11 = p11; }
          else {
            df00 = dsav00 - p00; df01 = dsav01 - p01;
            df10 = dsav10 - p10; df11 = dsav11 - p11;
          }
        } // e

        // redundant (identical) state update in every lane
        if (pot == 0) { st0.z -= df00; st0.w -= df01; st1.z -= df10; st1.w -= df11; }
        else          { st0.x += df00; st0.y += df01; st1.x += df10; st1.y += df11; }
      } // pot
    } // layer

    if (g == 0) {
        reinterpret_cast<float4*>(out)[r0] = st0;
        reinterpret_cast<float4*>(out)[r1] = st1;
    }
}

extern "C" void kernel_launch(void* const* d_in, const int* in_sizes, int n_in,
                              void* d_out, int out_size, void* d_ws, size_t ws_size,
                              hipStream_t stream) {
    const float* z   = (const float*)d_in[0];
    const float* t   = (const float*)d_in[1];
    const float* Wq1 = (const float*)d_in[2];
    const float* bq1 = (const float*)d_in[3];
    const float* Wq2 = (const float*)d_in[4];
    const float* bq2 = (const float*)d_in[5];
    const float* wq3 = (const float*)d_in[6];
    const float* Wp1 = (const float*)d_in[7];
    const float* bp1 = (const float*)d_in[8];
    const float* Wp2 = (const float*)d_in[9];
    const float* bp2 = (const float*)d_in[10];
    const float* wp3 = (const float*)d_in[11];
    float* out = (float*)d_out;

    const int B = in_sizes[1];          // 131072 rows
    const int blocks = B / RB;          // 1024 blocks

    sympnet_kernel<<<blocks, 256, 0, stream>>>(
        z, t, Wq1, bq1, Wq2, bq2, wq3, Wp1, bp1, Wp2, bp2, wp3, out);
}